// Round 4
// baseline (250.030 us; speedup 1.0000x reference)
//
#include <hip/hip_runtime.h>
#include <math.h>

#define L_SEQ   2048
#define BATCH_N 8
#define H_DIM   1024
#define P_DIM   512
#define M_DIM   (BATCH_N * L_SEQ)   // 16384
#define N2      1024                // packed complex width (re | im)
#define NC      32                  // scan chunks
#define T_CHUNK 64                  // L_SEQ / NC

typedef __attribute__((ext_vector_type(8))) __bf16 bf16x8;
typedef __attribute__((ext_vector_type(4))) float f32x4;

__device__ __forceinline__ unsigned f2bf_bits(float f) {
    unsigned u = __builtin_bit_cast(unsigned, f);
    return (u + 0x7fffu + ((u >> 16) & 1u)) >> 16;   // RNE
}
__device__ __forceinline__ float bf_lo(unsigned v) {
    return __builtin_bit_cast(float, v << 16);
}
__device__ __forceinline__ float bf_hi(unsigned v) {
    return __builtin_bit_cast(float, v & 0xffff0000u);
}

#define ASYNC_COPY16(gsrc, ldst)                                            \
    __builtin_amdgcn_global_load_lds(                                       \
        (__attribute__((address_space(1))) void*)(gsrc),                    \
        (__attribute__((address_space(3))) void*)(ldst), 16, 0, 0)

// ---------------------------------------------------------------------------
// lam buffer: [lam_re(512) | lam_im(512) | g_re(512) | g_im(512)]  (fp32)
// ---------------------------------------------------------------------------
__global__ void setup_lam(const float* __restrict__ Lre_in,
                          const float* __restrict__ Lim_in,
                          const float* __restrict__ log_step,
                          float* __restrict__ lam) {
    int p = blockIdx.x * blockDim.x + threadIdx.x;
    if (p >= P_DIM) return;
    float step = expf(log_step[p]);
    float c = Lre_in[p];
    float d = Lim_in[p];
    float mag = expf(c * step);
    float ang = d * step;
    float lr = mag * cosf(ang);
    float li = mag * sinf(ang);
    float a = lr - 1.0f, b = li;
    float inv = 1.0f / (c * c + d * d);
    lam[p]             = lr;
    lam[P_DIM + p]     = li;
    lam[2 * P_DIM + p] = (a * c + b * d) * inv;   // g_re
    lam[3 * P_DIM + p] = (b * c - a * d) * inv;   // g_im
}

// Fused weight build.
// W1[n][k] bf16 (N2 x H): n<512 -> B_bar_re, n>=512 -> B_bar_im
// W2[h][k] bf16 (H x N2): k<512 -> 2*C_re,   k>=512 -> -2*C_im
__global__ void build_W(const float* __restrict__ B,
                        const float* __restrict__ C,
                        const float* __restrict__ lam,
                        unsigned short* __restrict__ W1,
                        unsigned short* __restrict__ W2) {
    int idx = blockIdx.x * blockDim.x + threadIdx.x;
    if (idx < P_DIM * H_DIM) {                       // W1 half: idx over P*H
        int p = idx >> 10;
        int h = idx & (H_DIM - 1);
        float bre = B[(size_t)idx * 2];
        float bim = B[(size_t)idx * 2 + 1];
        float gre = lam[2 * P_DIM + p];
        float gim = lam[3 * P_DIM + p];
        W1[(size_t)p * H_DIM + h]           = (unsigned short)f2bf_bits(gre * bre - gim * bim);
        W1[(size_t)(P_DIM + p) * H_DIM + h] = (unsigned short)f2bf_bits(gre * bim + gim * bre);
    } else {                                         // W2 half: idx over H*P
        int j = idx - P_DIM * H_DIM;
        int h = j >> 9;
        int p = j & (P_DIM - 1);
        float cre = C[(size_t)j * 2];
        float cim = C[(size_t)j * 2 + 1];
        W2[(size_t)h * N2 + p]         = (unsigned short)f2bf_bits( 2.0f * cre);
        W2[(size_t)h * N2 + P_DIM + p] = (unsigned short)f2bf_bits(-2.0f * cim);
    }
}

// ---------------------------------------------------------------------------
// bf16 MFMA GEMM (round-0 structure: 128x128 tile, BK=64, 32 KB LDS,
// 256 thr = 4 waves 2x2, 4 blocks/CU -- best verified: 44 us/dispatch).
// Out[m][n] = sum_k A[m][k]*W[n][k].
//
// MODE 0 (GEMM1): A-source is the f32 signal, reg-staged in-kernel
//   (global float4 x2 -> f2bf_bits RNE -> ds_write_b128). This removes the
//   separate convert_sig pass + 32 MB sigbf buffer entirely. Bu output is
//   bit-identical to the old path (same RNE conversion). W via gload_lds.
// MODE 1 (GEMM2): A-source is Bubf bf16 via gload_lds (unchanged);
//   epilogue reads f32 signal directly for the D*sig term.
//
// LDS k-slot swizzle (round-0, verified): slot' = (slot + (row>>1)) & 7,
// via rotating the per-lane global source quad (qg) at stage time; fragment
// reads use sl = (kk*4 + fq + (fr>>1)) & 7. Note: SQ_LDS_BANK_CONFLICT
// shows a constant 4 cyc per ds_read_b128 with ANY swizzle (rounds 1-3
// A/B) -- structural wave64-b128 cost, not mis-banking. Do not chase it.
// XCD swizzle: XCD x owns m-blocks [16x, 16x+16); 8 n-blocks consecutive.
// ---------------------------------------------------------------------------
template <int MODE>
__global__ __launch_bounds__(256, 4) void gemm_mfma(
    const void* __restrict__ Asrc,
    const unsigned short* __restrict__ W,
    void* __restrict__ Out, int K,
    const float* __restrict__ Dvec, const float* __restrict__ SigF)
{
    __shared__ unsigned short smem[128 * 64 * 2];   // As 16K | Ws 16K
    unsigned short* As = smem;
    unsigned short* Ws = smem + 128 * 64;

    const int tid  = threadIdx.x;
    const int lane = tid & 63;
    const int wid  = tid >> 6;
    const int wm   = wid >> 1;     // 0..1
    const int wn   = wid & 1;      // 0..1

    // XCD swizzle: 128 m-blocks x 8 n-blocks, XCD x -> m-blocks [16x,16x+16)
    const int id  = blockIdx.x;
    const int xcd = id & 7;
    const int j   = id >> 3;              // 0..127
    const int mb  = xcd * 16 + (j >> 3);  // m-block (128 rows)
    const int nb  = j & 7;                // n-block (128 cols)
    const int m0 = mb * 128;
    const int n0 = nb * 128;

    // --- staging geometry (swizzled) --------------------------------------
    const int srow = tid >> 3;                                  // 0..31
    const int qg   = ((tid & 7) - ((tid >> 4) & 7)) & 7;        // const/lane
    const unsigned short* Abf = (const unsigned short*)Asrc
        + (size_t)(m0 + srow) * K + qg * 8;                     // MODE 1
    const float* Af = (const float*)Asrc
        + (size_t)(m0 + srow) * K + qg * 8;                     // MODE 0
    const unsigned short* Wbase = W + (size_t)(n0 + srow) * K + qg * 8;

    const int fr = lane & 15;        // m-row / n-col within 16
    const int fq = (lane >> 4) & 3;  // k-quad within 32
    const int sw = fr >> 1;          // swizzle rotation for this lane

    f32x4 acc[4][4] = {};

    for (int k0 = 0; k0 < K; k0 += 64) {
        __syncthreads();
        #pragma unroll
        for (int i = 0; i < 4; ++i)      // W: 1024 chunks, async DMA first
            ASYNC_COPY16(Wbase + (size_t)(i * 32) * K + k0,
                         Ws + (size_t)(i * 256 + wid * 64) * 8);
        if (MODE == 0) {
            // A: reg-staged from f32 signal, converted to bf16 in-kernel
            #pragma unroll
            for (int i = 0; i < 4; ++i) {
                const float* s = Af + (size_t)(i * 32) * K + k0;
                float4 v0 = *(const float4*)s;
                float4 v1 = *(const float4*)(s + 4);
                uint4 pk;
                pk.x = f2bf_bits(v0.x) | (f2bf_bits(v0.y) << 16);
                pk.y = f2bf_bits(v0.z) | (f2bf_bits(v0.w) << 16);
                pk.z = f2bf_bits(v1.x) | (f2bf_bits(v1.y) << 16);
                pk.w = f2bf_bits(v1.z) | (f2bf_bits(v1.w) << 16);
                *(uint4*)(As + ((size_t)i * 256 + tid) * 8) = pk;
            }
        } else {
            #pragma unroll
            for (int i = 0; i < 4; ++i)
                ASYNC_COPY16(Abf + (size_t)(i * 32) * K + k0,
                             As + (size_t)(i * 256 + wid * 64) * 8);
        }
        __syncthreads();

        #pragma unroll
        for (int kk = 0; kk < 2; ++kk) {
            bf16x8 af[4], wf[4];
            #pragma unroll
            for (int mi = 0; mi < 4; ++mi) {
                int row = wm * 64 + mi * 16 + fr;
                int sl  = (kk * 4 + fq + sw) & 7;
                af[mi] = *(const bf16x8*)&As[(size_t)row * 64 + sl * 8];
            }
            #pragma unroll
            for (int ni = 0; ni < 4; ++ni) {
                int row = wn * 64 + ni * 16 + fr;
                int sl  = (kk * 4 + fq + sw) & 7;
                wf[ni] = *(const bf16x8*)&Ws[(size_t)row * 64 + sl * 8];
            }
            #pragma unroll
            for (int mi = 0; mi < 4; ++mi)
                #pragma unroll
                for (int ni = 0; ni < 4; ++ni)
                    acc[mi][ni] = __builtin_amdgcn_mfma_f32_16x16x32_bf16(
                        af[mi], wf[ni], acc[mi][ni], 0, 0, 0);
        }
    }

    // C/D layout (m89): col = lane&15, row = (lane>>4)*4 + reg
    if (MODE == 0) {
        // bf16 out: transpose through LDS (two 64x128 half-tiles, 16 KB)
        unsigned short* T = smem;
        #pragma unroll
        for (int h = 0; h < 2; ++h) {
            __syncthreads();       // prior LDS readers done
            if (wm == h) {
                #pragma unroll
                for (int mi = 0; mi < 4; ++mi)
                    #pragma unroll
                    for (int ni = 0; ni < 4; ++ni)
                        #pragma unroll
                        for (int r = 0; r < 4; ++r) {
                            int lrow = mi * 16 + fq * 4 + r;      // 0..63
                            int lcol = wn * 64 + ni * 16 + fr;    // 0..127
                            T[lrow * 128 + lcol] =
                                (unsigned short)f2bf_bits(acc[mi][ni][r]);
                        }
            }
            __syncthreads();
            // 64 rows x 128 cols = 1024 chunks of 8 ushorts (16 B)
            #pragma unroll
            for (int jj = 0; jj < 4; ++jj) {
                int chunk = jj * 256 + tid;        // 0..1023
                int row = chunk >> 4;              // 0..63
                int co  = (chunk & 15) * 8;        // 0..120
                *(ulonglong2*)((unsigned short*)Out +
                    (size_t)(m0 + h * 64 + row) * 1024 + n0 + co) =
                    *(const ulonglong2*)&T[row * 128 + co];
            }
        }
    } else {
        float Dl[4];
        #pragma unroll
        for (int ni = 0; ni < 4; ++ni)
            Dl[ni] = Dvec[n0 + wn * 64 + ni * 16 + fr];
        #pragma unroll
        for (int mi = 0; mi < 4; ++mi) {
            #pragma unroll
            for (int ni = 0; ni < 4; ++ni) {
                #pragma unroll
                for (int r = 0; r < 4; ++r) {
                    int row = m0 + wm * 64 + mi * 16 + fq * 4 + r;
                    int col = n0 + wn * 64 + ni * 16 + fr;
                    float v = acc[mi][ni][r];
                    v = fmaf(Dl[ni], SigF[(size_t)row * 1024 + col], v);
                    ((float*)Out)[(size_t)row * 1024 + col] = v;
                }
            }
        }
    }
}

// ---------------------------------------------------------------------------
// Scan pass A: per (b, chunk) local scan (zero init) -> chunk-end sums.
// Load pipeline: 2-stage ping-pong (named buffers, static indices) so each
// 16-load group is in flight while the previous group's FMA chain runs.
// ---------------------------------------------------------------------------
#define SCAN_LOADG(R, I, j0)                                                \
    _Pragma("unroll")                                                       \
    for (int j = 0; j < 8; ++j) {                                           \
        R[j] = base[(size_t)((j0) + j) * 512 + t];                          \
        I[j] = base[(size_t)((j0) + j) * 512 + 256 + t];                    \
    }

#define SCAN_COMP(R, I)                                                     \
    _Pragma("unroll")                                                       \
    for (int j = 0; j < 8; ++j) {                                           \
        float nr0 = fmaf(lr0, xr0, fmaf(-li0, xi0, bf_lo(R[j])));           \
        float ni0 = fmaf(lr0, xi0, fmaf( li0, xr0, bf_lo(I[j])));           \
        float nr1 = fmaf(lr1, xr1, fmaf(-li1, xi1, bf_hi(R[j])));           \
        float ni1 = fmaf(lr1, xi1, fmaf( li1, xr1, bf_hi(I[j])));           \
        xr0 = nr0; xi0 = ni0; xr1 = nr1; xi1 = ni1;                         \
    }

__global__ __launch_bounds__(256) void scan_sums(
    const unsigned short* __restrict__ Bu, const float* __restrict__ lam,
    float* __restrict__ S)
{
    int b = blockIdx.x, c = blockIdx.y, t = threadIdx.x;
    int p0 = 2 * t, p1 = 2 * t + 1;
    float lr0 = lam[p0], li0 = lam[P_DIM + p0];
    float lr1 = lam[p1], li1 = lam[P_DIM + p1];
    const unsigned* base =
        (const unsigned*)(Bu + ((size_t)b * L_SEQ + (size_t)c * T_CHUNK) * N2);
    float xr0 = 0, xi0 = 0, xr1 = 0, xi1 = 0;
    unsigned R0[8], I0[8], R1[8], I1[8];
    SCAN_LOADG(R0, I0, 0)
    #pragma unroll
    for (int gg = 0; gg < 4; ++gg) {
        SCAN_LOADG(R1, I1, gg * 16 + 8)
        SCAN_COMP(R0, I0)
        if (gg < 3) { SCAN_LOADG(R0, I0, gg * 16 + 16) }
        SCAN_COMP(R1, I1)
    }
    float* Sb = S + ((size_t)(b * NC + c) * 2) * P_DIM;
    Sb[p0] = xr0; Sb[p1] = xr1;
    Sb[P_DIM + p0] = xi0; Sb[P_DIM + p1] = xi1;
}

// Pass B: carries. cin[b][0]=0; cin[c] = lam^T_CHUNK * cin[c-1] + S[c-1].
// All 32 S-values preloaded upfront (64 independent loads, static regs) so
// the serial chain runs entirely in registers -- one memory latency, not 32.
__global__ __launch_bounds__(512) void scan_carry(
    const float* __restrict__ S, const float* __restrict__ lam,
    float* __restrict__ CIN)
{
    int b = blockIdx.x, p = threadIdx.x;
    float lr = lam[p], li = lam[P_DIM + p];
    float pr = lr, pi = li;                 // lam^64 via 6 squarings
    #pragma unroll
    for (int i = 0; i < 6; ++i) {
        float nr = pr * pr - pi * pi;
        float ni = 2.0f * pr * pi;
        pr = nr; pi = ni;
    }
    float sr[NC], si[NC];
    #pragma unroll
    for (int c = 0; c < NC; ++c) {
        const float* Sb = S + ((size_t)(b * NC + c) * 2) * P_DIM;
        sr[c] = Sb[p];
        si[c] = Sb[P_DIM + p];
    }
    float cr = 0, ci = 0;
    #pragma unroll
    for (int c = 0; c < NC; ++c) {
        float* Cb = CIN + ((size_t)(b * NC + c) * 2) * P_DIM;
        Cb[p] = cr; Cb[P_DIM + p] = ci;
        float nr = fmaf(pr, cr, fmaf(-pi, ci, sr[c]));
        float ni = fmaf(pr, ci, fmaf( pi, cr, si[c]));
        cr = nr; ci = ni;
    }
}

// Pass C: x = cin; x = lam*x + u; overwrite Bu with xs (bf16); emit state.
// Same 2-stage load ping-pong as pass A; stores happen inside COMPST.
#define SCAN_COMPST(R, I, j0)                                               \
    _Pragma("unroll")                                                       \
    for (int j = 0; j < 8; ++j) {                                           \
        float nr0 = fmaf(lr0, xr0, fmaf(-li0, xi0, bf_lo(R[j])));           \
        float ni0 = fmaf(lr0, xi0, fmaf( li0, xr0, bf_lo(I[j])));           \
        float nr1 = fmaf(lr1, xr1, fmaf(-li1, xi1, bf_hi(R[j])));           \
        float ni1 = fmaf(lr1, xi1, fmaf( li1, xr1, bf_hi(I[j])));           \
        xr0 = nr0; xi0 = ni0; xr1 = nr1; xi1 = ni1;                         \
        R[j] = f2bf_bits(nr0) | (f2bf_bits(nr1) << 16);                     \
        I[j] = f2bf_bits(ni0) | (f2bf_bits(ni1) << 16);                     \
    }                                                                       \
    _Pragma("unroll")                                                       \
    for (int j = 0; j < 8; ++j) {                                           \
        base[(size_t)((j0) + j) * 512 + t]       = R[j];                    \
        base[(size_t)((j0) + j) * 512 + 256 + t] = I[j];                    \
    }

__global__ __launch_bounds__(256) void scan_apply(
    unsigned short* __restrict__ Bu, const float* __restrict__ lam,
    const float* __restrict__ CIN, float* __restrict__ out_state,
    int interleaved)
{
    int b = blockIdx.x, c = blockIdx.y, t = threadIdx.x;
    int p0 = 2 * t, p1 = 2 * t + 1;
    float lr0 = lam[p0], li0 = lam[P_DIM + p0];
    float lr1 = lam[p1], li1 = lam[P_DIM + p1];
    const float* Cb = CIN + ((size_t)(b * NC + c) * 2) * P_DIM;
    float xr0 = Cb[p0], xi0 = Cb[P_DIM + p0];
    float xr1 = Cb[p1], xi1 = Cb[P_DIM + p1];
    unsigned* base =
        (unsigned*)(Bu + ((size_t)b * L_SEQ + (size_t)c * T_CHUNK) * N2);
    unsigned R0[8], I0[8], R1[8], I1[8];
    SCAN_LOADG(R0, I0, 0)
    #pragma unroll
    for (int gg = 0; gg < 4; ++gg) {
        SCAN_LOADG(R1, I1, gg * 16 + 8)
        SCAN_COMPST(R0, I0, gg * 16)
        if (gg < 3) { SCAN_LOADG(R0, I0, gg * 16 + 16) }
        SCAN_COMPST(R1, I1, gg * 16 + 8)
    }
    if (c == NC - 1) {
        if (interleaved) {
            out_state[((size_t)b * P_DIM + p0) * 2]     = xr0;
            out_state[((size_t)b * P_DIM + p0) * 2 + 1] = xi0;
            out_state[((size_t)b * P_DIM + p1) * 2]     = xr1;
            out_state[((size_t)b * P_DIM + p1) * 2 + 1] = xi1;
        } else {
            out_state[(size_t)b * P_DIM + p0] = xr0;
            out_state[(size_t)b * P_DIM + p1] = xr1;
        }
    }
}

// ---------------------------------------------------------------------------
extern "C" void kernel_launch(void* const* d_in, const int* in_sizes, int n_in,
                              void* d_out, int out_size, void* d_ws, size_t ws_size,
                              hipStream_t stream)
{
    const float* signal   = (const float*)d_in[0];
    // d_in[1] = prev_state: never reaches the scan's b-component -> no effect
    const float* Lre      = (const float*)d_in[2];
    const float* Lim      = (const float*)d_in[3];
    const float* B        = (const float*)d_in[4];
    const float* C        = (const float*)d_in[5];
    const float* Dv       = (const float*)d_in[6];
    const float* log_step = (const float*)d_in[7];

    // ws layout (bytes) -- sigbf eliminated (GEMM1 converts in-kernel)
    char* ws = (char*)d_ws;
    unsigned short* Bubf  = (unsigned short*)ws;                      // 32 MB
    unsigned short* W1bf  = (unsigned short*)(ws + 33554432);         // 2 MB
    unsigned short* W2bf  = (unsigned short*)(ws + 35651584);         // 2 MB
    float*          lam   = (float*)(ws + 37748736);                  // 8 KB
    float*          S     = (float*)(ws + 37756928);                  // 512 KB
    float*          CIN   = (float*)(ws + 38281216);                  // 512 KB
    size_t need = 38805504;
    if (ws_size < need) return;

    float* y_out = (float*)d_out;
    float* state_out = y_out + (size_t)M_DIM * H_DIM;
    int interleaved = (out_size - M_DIM * H_DIM) >= 2 * BATCH_N * P_DIM;

    setup_lam<<<dim3(2), dim3(256), 0, stream>>>(Lre, Lim, log_step, lam);
    build_W<<<dim3((2 * P_DIM * H_DIM) / 256), dim3(256), 0, stream>>>(
        B, C, lam, W1bf, W2bf);

    // GEMM1: Bu[m][n] = sum_h sig[m][h] * W1[n][h]   (bf16 out, A = f32 sig)
    gemm_mfma<0><<<dim3(1024), dim3(256), 0, stream>>>(
        signal, W1bf, Bubf, H_DIM, nullptr, nullptr);

    scan_sums<<<dim3(BATCH_N, NC), dim3(256), 0, stream>>>(Bubf, lam, S);
    scan_carry<<<dim3(BATCH_N), dim3(512), 0, stream>>>(S, lam, CIN);
    scan_apply<<<dim3(BATCH_N, NC), dim3(256), 0, stream>>>(
        Bubf, lam, CIN, state_out, interleaved);

    // GEMM2: y[m][h] = sum_k xs[m][k]*W2[h][k] + D[h]*sig[m][h]  (fp32 out)
    gemm_mfma<1><<<dim3(1024), dim3(256), 0, stream>>>(
        Bubf, W2bf, y_out, N2, Dv, signal);
}

// Round 5
// 230.097 us; speedup vs baseline: 1.0866x; 1.0866x over previous
//
#include <hip/hip_runtime.h>
#include <math.h>

#define L_SEQ   2048
#define BATCH_N 8
#define H_DIM   1024
#define P_DIM   512
#define M_DIM   (BATCH_N * L_SEQ)   // 16384
#define N2      1024                // packed complex width (re | im)
#define NC      32                  // scan chunks
#define T_CHUNK 64                  // L_SEQ / NC

typedef __attribute__((ext_vector_type(8))) __bf16 bf16x8;
typedef __attribute__((ext_vector_type(4))) float f32x4;

__device__ __forceinline__ unsigned f2bf_bits(float f) {
    unsigned u = __builtin_bit_cast(unsigned, f);
    return (u + 0x7fffu + ((u >> 16) & 1u)) >> 16;   // RNE
}
__device__ __forceinline__ float bf_lo(unsigned v) {
    return __builtin_bit_cast(float, v << 16);
}
__device__ __forceinline__ float bf_hi(unsigned v) {
    return __builtin_bit_cast(float, v & 0xffff0000u);
}
__device__ __forceinline__ float bf2f(unsigned short u) {
    return __builtin_bit_cast(float, (unsigned)u << 16);
}

#define ASYNC_COPY16(gsrc, ldst)                                            \
    __builtin_amdgcn_global_load_lds(                                       \
        (__attribute__((address_space(1))) void*)(gsrc),                    \
        (__attribute__((address_space(3))) void*)(ldst), 16, 0, 0)

// ---------------------------------------------------------------------------
// lam buffer: [lam_re(512) | lam_im(512) | g_re(512) | g_im(512)]  (fp32)
// ---------------------------------------------------------------------------
__global__ void setup_lam(const float* __restrict__ Lre_in,
                          const float* __restrict__ Lim_in,
                          const float* __restrict__ log_step,
                          float* __restrict__ lam) {
    int p = blockIdx.x * blockDim.x + threadIdx.x;
    if (p >= P_DIM) return;
    float step = expf(log_step[p]);
    float c = Lre_in[p];
    float d = Lim_in[p];
    float mag = expf(c * step);
    float ang = d * step;
    float lr = mag * cosf(ang);
    float li = mag * sinf(ang);
    float a = lr - 1.0f, b = li;
    float inv = 1.0f / (c * c + d * d);
    lam[p]             = lr;
    lam[P_DIM + p]     = li;
    lam[2 * P_DIM + p] = (a * c + b * d) * inv;   // g_re
    lam[3 * P_DIM + p] = (b * c - a * d) * inv;   // g_im
}

// Fused weight build.
// W1[n][k] bf16 (N2 x H): n<512 -> B_bar_re, n>=512 -> B_bar_im
// W2[h][k] bf16 (H x N2): k<512 -> 2*C_re,   k>=512 -> -2*C_im
__global__ void build_W(const float* __restrict__ B,
                        const float* __restrict__ C,
                        const float* __restrict__ lam,
                        unsigned short* __restrict__ W1,
                        unsigned short* __restrict__ W2) {
    int idx = blockIdx.x * blockDim.x + threadIdx.x;
    if (idx < P_DIM * H_DIM) {                       // W1 half: idx over P*H
        int p = idx >> 10;
        int h = idx & (H_DIM - 1);
        float bre = B[(size_t)idx * 2];
        float bim = B[(size_t)idx * 2 + 1];
        float gre = lam[2 * P_DIM + p];
        float gim = lam[3 * P_DIM + p];
        W1[(size_t)p * H_DIM + h]           = (unsigned short)f2bf_bits(gre * bre - gim * bim);
        W1[(size_t)(P_DIM + p) * H_DIM + h] = (unsigned short)f2bf_bits(gre * bim + gim * bre);
    } else {                                         // W2 half: idx over H*P
        int j = idx - P_DIM * H_DIM;
        int h = j >> 9;
        int p = j & (P_DIM - 1);
        float cre = C[(size_t)j * 2];
        float cim = C[(size_t)j * 2 + 1];
        W2[(size_t)h * N2 + p]         = (unsigned short)f2bf_bits( 2.0f * cre);
        W2[(size_t)h * N2 + P_DIM + p] = (unsigned short)f2bf_bits(-2.0f * cim);
    }
}

__global__ void convert_sig(const float* __restrict__ in,
                            unsigned short* __restrict__ out) {
    size_t i = ((size_t)blockIdx.x * 256 + threadIdx.x) * 4;
    float4 v = *(const float4*)(in + i);
    ushort4 o;
    o.x = (unsigned short)f2bf_bits(v.x);
    o.y = (unsigned short)f2bf_bits(v.y);
    o.z = (unsigned short)f2bf_bits(v.z);
    o.w = (unsigned short)f2bf_bits(v.w);
    *(ushort4*)(out + i) = o;
}

// ---------------------------------------------------------------------------
// bf16 MFMA GEMM (round-0 verified structure -- best measured: 44 us).
// Out[m][n] = sum_k A[m][k]*W[n][k].
// A: M x K bf16 row-major, W: N x K bf16 row-major (K = 1024).
// Block tile 128(m) x 128(n), BK=64, LDS 32 KB. 256 thr = 4 waves in 2x2;
// wave tile 64x64 = 4x4 frags of 16x16x32 MFMA (verified layout).
// Grid 1024, __launch_bounds__(256,4) -> 4 blocks/CU (16 waves): barrier
// drains overlap across blocks.
// LDS k-slot swizzle: slot' = (slot + (row>>1)) & 7, via rotating the
// *global* source quad per lane at stage time. NOTE (rounds 1-3 A/B):
// SQ_LDS_BANK_CONFLICT is a constant 4 cyc per ds_read_b128 under ANY
// swizzle -- structural wave64-b128 cost, not mis-banking. Do not chase.
// XCD swizzle: XCD x owns m-blocks [16x, 16x+16); 8 n-blocks consecutive.
// MODE 0: bf16 out via LDS-transposed coalesced 16B stores (2 phases).
// MODE 1: f32 out, + D[col]*bf2f(SigBf[row][col]) fused.
// ---------------------------------------------------------------------------
template <int MODE>
__global__ __launch_bounds__(256, 4) void gemm_mfma(
    const unsigned short* __restrict__ A,
    const unsigned short* __restrict__ W,
    void* __restrict__ Out, int K,
    const float* __restrict__ Dvec, const unsigned short* __restrict__ SigBf)
{
    __shared__ unsigned short smem[128 * 64 * 2];   // As 16K | Ws 16K
    unsigned short* As = smem;
    unsigned short* Ws = smem + 128 * 64;

    const int tid  = threadIdx.x;
    const int lane = tid & 63;
    const int wid  = tid >> 6;
    const int wm   = wid >> 1;     // 0..1
    const int wn   = wid & 1;      // 0..1

    // XCD swizzle: 128 m-blocks x 8 n-blocks, XCD x -> m-blocks [16x,16x+16)
    const int id  = blockIdx.x;
    const int xcd = id & 7;
    const int j   = id >> 3;              // 0..127
    const int mb  = xcd * 16 + (j >> 3);  // m-block (128 rows)
    const int nb  = j & 7;                // n-block (128 cols)
    const int m0 = mb * 128;
    const int n0 = nb * 128;

    // --- staging geometry (swizzled) --------------------------------------
    const int srow = tid >> 3;                                  // 0..31
    const int qg   = ((tid & 7) - ((tid >> 4) & 7)) & 7;        // const/lane
    const unsigned short* Abase = A + (size_t)(m0 + srow) * K + qg * 8;
    const unsigned short* Wbase = W + (size_t)(n0 + srow) * K + qg * 8;

    const int fr = lane & 15;        // m-row / n-col within 16
    const int fq = (lane >> 4) & 3;  // k-quad within 32
    const int sw = fr >> 1;          // swizzle rotation for this lane

    f32x4 acc[4][4] = {};

    for (int k0 = 0; k0 < K; k0 += 64) {
        __syncthreads();
        #pragma unroll
        for (int i = 0; i < 4; ++i)      // A: 1024 chunks (128 rows x 8 slots)
            ASYNC_COPY16(Abase + (size_t)(i * 32) * K + k0,
                         As + (size_t)(i * 256 + wid * 64) * 8);
        #pragma unroll
        for (int i = 0; i < 4; ++i)      // W: 1024 chunks
            ASYNC_COPY16(Wbase + (size_t)(i * 32) * K + k0,
                         Ws + (size_t)(i * 256 + wid * 64) * 8);
        __syncthreads();

        #pragma unroll
        for (int kk = 0; kk < 2; ++kk) {
            bf16x8 af[4], wf[4];
            #pragma unroll
            for (int mi = 0; mi < 4; ++mi) {
                int row = wm * 64 + mi * 16 + fr;
                int sl  = (kk * 4 + fq + sw) & 7;
                af[mi] = *(const bf16x8*)&As[(size_t)row * 64 + sl * 8];
            }
            #pragma unroll
            for (int ni = 0; ni < 4; ++ni) {
                int row = wn * 64 + ni * 16 + fr;
                int sl  = (kk * 4 + fq + sw) & 7;
                wf[ni] = *(const bf16x8*)&Ws[(size_t)row * 64 + sl * 8];
            }
            #pragma unroll
            for (int mi = 0; mi < 4; ++mi)
                #pragma unroll
                for (int ni = 0; ni < 4; ++ni)
                    acc[mi][ni] = __builtin_amdgcn_mfma_f32_16x16x32_bf16(
                        af[mi], wf[ni], acc[mi][ni], 0, 0, 0);
        }
    }

    // C/D layout (m89): col = lane&15, row = (lane>>4)*4 + reg
    if (MODE == 0) {
        // bf16 out: transpose through LDS (two 64x128 half-tiles, 16 KB)
        unsigned short* T = smem;
        #pragma unroll
        for (int h = 0; h < 2; ++h) {
            __syncthreads();       // prior LDS readers done
            if (wm == h) {
                #pragma unroll
                for (int mi = 0; mi < 4; ++mi)
                    #pragma unroll
                    for (int ni = 0; ni < 4; ++ni)
                        #pragma unroll
                        for (int r = 0; r < 4; ++r) {
                            int lrow = mi * 16 + fq * 4 + r;      // 0..63
                            int lcol = wn * 64 + ni * 16 + fr;    // 0..127
                            T[lrow * 128 + lcol] =
                                (unsigned short)f2bf_bits(acc[mi][ni][r]);
                        }
            }
            __syncthreads();
            // 64 rows x 128 cols = 1024 chunks of 8 ushorts (16 B)
            #pragma unroll
            for (int jj = 0; jj < 4; ++jj) {
                int chunk = jj * 256 + tid;        // 0..1023
                int row = chunk >> 4;              // 0..63
                int co  = (chunk & 15) * 8;        // 0..120
                *(ulonglong2*)((unsigned short*)Out +
                    (size_t)(m0 + h * 64 + row) * 1024 + n0 + co) =
                    *(const ulonglong2*)&T[row * 128 + co];
            }
        }
    } else {
        float Dl[4];
        #pragma unroll
        for (int ni = 0; ni < 4; ++ni)
            Dl[ni] = Dvec[n0 + wn * 64 + ni * 16 + fr];
        #pragma unroll
        for (int mi = 0; mi < 4; ++mi) {
            #pragma unroll
            for (int ni = 0; ni < 4; ++ni) {
                #pragma unroll
                for (int r = 0; r < 4; ++r) {
                    int row = m0 + wm * 64 + mi * 16 + fq * 4 + r;
                    int col = n0 + wn * 64 + ni * 16 + fr;
                    float v = acc[mi][ni][r];
                    v = fmaf(Dl[ni], bf2f(SigBf[(size_t)row * 1024 + col]), v);
                    ((float*)Out)[(size_t)row * 1024 + col] = v;
                }
            }
        }
    }
}

// ---------------------------------------------------------------------------
// Scan pass A: per (b, chunk) local scan (zero init) -> chunk-end sums.
// (round-0 verified version)
// ---------------------------------------------------------------------------
__global__ __launch_bounds__(256) void scan_sums(
    const unsigned short* __restrict__ Bu, const float* __restrict__ lam,
    float* __restrict__ S)
{
    int b = blockIdx.x, c = blockIdx.y, t = threadIdx.x;
    int p0 = 2 * t, p1 = 2 * t + 1;
    float lr0 = lam[p0], li0 = lam[P_DIM + p0];
    float lr1 = lam[p1], li1 = lam[P_DIM + p1];
    const unsigned* base =
        (const unsigned*)(Bu + ((size_t)b * L_SEQ + (size_t)c * T_CHUNK) * N2);
    float xr0 = 0, xi0 = 0, xr1 = 0, xi1 = 0;
    for (int j0 = 0; j0 < T_CHUNK; j0 += 8) {
        unsigned R[8], I[8];
        #pragma unroll
        for (int j = 0; j < 8; ++j) {
            R[j] = base[(size_t)(j0 + j) * 512 + t];
            I[j] = base[(size_t)(j0 + j) * 512 + 256 + t];
        }
        #pragma unroll
        for (int j = 0; j < 8; ++j) {
            float nr0 = fmaf(lr0, xr0, fmaf(-li0, xi0, bf_lo(R[j])));
            float ni0 = fmaf(lr0, xi0, fmaf( li0, xr0, bf_lo(I[j])));
            float nr1 = fmaf(lr1, xr1, fmaf(-li1, xi1, bf_hi(R[j])));
            float ni1 = fmaf(lr1, xi1, fmaf( li1, xr1, bf_hi(I[j])));
            xr0 = nr0; xi0 = ni0; xr1 = nr1; xi1 = ni1;
        }
    }
    float* Sb = S + ((size_t)(b * NC + c) * 2) * P_DIM;
    Sb[p0] = xr0; Sb[p1] = xr1;
    Sb[P_DIM + p0] = xi0; Sb[P_DIM + p1] = xi1;
}

// ---------------------------------------------------------------------------
// Pass B+C fused: each (b,c) block derives its OWN carry-in from S via a
// 31-step Horner recurrence (statically preloaded float2 regs, predicated
// capture at k==c -- all indices compile-time, stays in registers), then
// applies the chunk scan and overwrites Bu with xs (bf16); emits state.
// Replaces the old 8-block scan_carry kernel + CIN round-trip entirely.
//   cin[c] = sum_{k<c} P^{c-1-k} S[k],  P = lam^T_CHUNK (6 squarings).
// Redundant across c-blocks but ~400 VALU ops/thread -- noise.
// ---------------------------------------------------------------------------
__global__ __launch_bounds__(256) void scan_apply(
    unsigned short* __restrict__ Bu, const float* __restrict__ lam,
    const float* __restrict__ S, float* __restrict__ out_state,
    int interleaved)
{
    int b = blockIdx.x, c = blockIdx.y, t = threadIdx.x;
    int p0 = 2 * t, p1 = 2 * t + 1;
    float lr0 = lam[p0], li0 = lam[P_DIM + p0];
    float lr1 = lam[p1], li1 = lam[P_DIM + p1];

    // P = lam^T_CHUNK via 6 squarings (per p)
    float pr0 = lr0, pi0 = li0, pr1 = lr1, pi1 = li1;
    #pragma unroll
    for (int i = 0; i < 6; ++i) {
        float a0 = pr0 * pr0 - pi0 * pi0, b0 = 2.0f * pr0 * pi0;
        float a1 = pr1 * pr1 - pi1 * pi1, b1 = 2.0f * pr1 * pi1;
        pr0 = a0; pi0 = b0; pr1 = a1; pi1 = b1;
    }

    // preload S[k], k=0..30 (float2: consecutive p0,p1) -- static unroll
    float2 sre[NC - 1], sim[NC - 1];
    #pragma unroll
    for (int k = 0; k < NC - 1; ++k) {
        const float* Sb = S + ((size_t)(b * NC + k) * 2) * P_DIM;
        sre[k] = *(const float2*)&Sb[p0];
        sim[k] = *(const float2*)&Sb[P_DIM + p0];
    }

    // Horner prefix with predicated capture: cin[c]
    float xr0 = 0, xi0 = 0, xr1 = 0, xi1 = 0;
    float cr0 = 0, ci0 = 0, cr1 = 0, ci1 = 0;
    #pragma unroll
    for (int k = 0; k < NC - 1; ++k) {
        if (k == c) { cr0 = xr0; ci0 = xi0; cr1 = xr1; ci1 = xi1; }
        float nr0 = fmaf(pr0, xr0, fmaf(-pi0, xi0, sre[k].x));
        float ni0 = fmaf(pr0, xi0, fmaf( pi0, xr0, sim[k].x));
        float nr1 = fmaf(pr1, xr1, fmaf(-pi1, xi1, sre[k].y));
        float ni1 = fmaf(pr1, xi1, fmaf( pi1, xr1, sim[k].y));
        xr0 = nr0; xi0 = ni0; xr1 = nr1; xi1 = ni1;
    }
    if (c == NC - 1) { cr0 = xr0; ci0 = xi0; cr1 = xr1; ci1 = xi1; }

    // apply chunk scan starting from cin
    xr0 = cr0; xi0 = ci0; xr1 = cr1; xi1 = ci1;
    unsigned* base =
        (unsigned*)(Bu + ((size_t)b * L_SEQ + (size_t)c * T_CHUNK) * N2);
    for (int j0 = 0; j0 < T_CHUNK; j0 += 8) {
        unsigned R[8], I[8];
        #pragma unroll
        for (int j = 0; j < 8; ++j) {
            R[j] = base[(size_t)(j0 + j) * 512 + t];
            I[j] = base[(size_t)(j0 + j) * 512 + 256 + t];
        }
        #pragma unroll
        for (int j = 0; j < 8; ++j) {
            float nr0 = fmaf(lr0, xr0, fmaf(-li0, xi0, bf_lo(R[j])));
            float ni0 = fmaf(lr0, xi0, fmaf( li0, xr0, bf_lo(I[j])));
            float nr1 = fmaf(lr1, xr1, fmaf(-li1, xi1, bf_hi(R[j])));
            float ni1 = fmaf(lr1, xi1, fmaf( li1, xr1, bf_hi(I[j])));
            xr0 = nr0; xi0 = ni0; xr1 = nr1; xi1 = ni1;
            R[j] = f2bf_bits(nr0) | (f2bf_bits(nr1) << 16);
            I[j] = f2bf_bits(ni0) | (f2bf_bits(ni1) << 16);
        }
        #pragma unroll
        for (int j = 0; j < 8; ++j) {
            base[(size_t)(j0 + j) * 512 + t]       = R[j];
            base[(size_t)(j0 + j) * 512 + 256 + t] = I[j];
        }
    }
    if (c == NC - 1) {
        if (interleaved) {
            out_state[((size_t)b * P_DIM + p0) * 2]     = xr0;
            out_state[((size_t)b * P_DIM + p0) * 2 + 1] = xi0;
            out_state[((size_t)b * P_DIM + p1) * 2]     = xr1;
            out_state[((size_t)b * P_DIM + p1) * 2 + 1] = xi1;
        } else {
            out_state[(size_t)b * P_DIM + p0] = xr0;
            out_state[(size_t)b * P_DIM + p1] = xr1;
        }
    }
}

// ---------------------------------------------------------------------------
extern "C" void kernel_launch(void* const* d_in, const int* in_sizes, int n_in,
                              void* d_out, int out_size, void* d_ws, size_t ws_size,
                              hipStream_t stream)
{
    const float* signal   = (const float*)d_in[0];
    // d_in[1] = prev_state: never reaches the scan's b-component -> no effect
    const float* Lre      = (const float*)d_in[2];
    const float* Lim      = (const float*)d_in[3];
    const float* B        = (const float*)d_in[4];
    const float* C        = (const float*)d_in[5];
    const float* Dv       = (const float*)d_in[6];
    const float* log_step = (const float*)d_in[7];

    // ws layout (bytes)
    char* ws = (char*)d_ws;
    unsigned short* sigbf = (unsigned short*)ws;                      // 32 MB
    unsigned short* Bubf  = (unsigned short*)(ws + 33554432);         // 32 MB
    unsigned short* W1bf  = (unsigned short*)(ws + 67108864);         // 2 MB
    unsigned short* W2bf  = (unsigned short*)(ws + 69206016);         // 2 MB
    float*          lam   = (float*)(ws + 71303168);                  // 8 KB
    float*          S     = (float*)(ws + 71311360);                  // 512 KB
    size_t need = 71835648;
    if (ws_size < need) return;

    float* y_out = (float*)d_out;
    float* state_out = y_out + (size_t)M_DIM * H_DIM;
    int interleaved = (out_size - M_DIM * H_DIM) >= 2 * BATCH_N * P_DIM;

    setup_lam<<<dim3(2), dim3(256), 0, stream>>>(Lre, Lim, log_step, lam);
    build_W<<<dim3((2 * P_DIM * H_DIM) / 256), dim3(256), 0, stream>>>(
        B, C, lam, W1bf, W2bf);
    convert_sig<<<dim3((M_DIM * H_DIM) / 1024), dim3(256), 0, stream>>>(signal, sigbf);

    // GEMM1: Bu[m][n] = sum_h sig[m][h] * W1[n][h]   (bf16 out)
    gemm_mfma<0><<<dim3(1024), dim3(256), 0, stream>>>(
        sigbf, W1bf, Bubf, H_DIM, nullptr, nullptr);

    scan_sums<<<dim3(BATCH_N, NC), dim3(256), 0, stream>>>(Bubf, lam, S);
    scan_apply<<<dim3(BATCH_N, NC), dim3(256), 0, stream>>>(
        Bubf, lam, S, state_out, interleaved);

    // GEMM2: y[m][h] = sum_k xs[m][k]*W2[h][k] + D[h]*sig[m][h]  (fp32 out)
    gemm_mfma<1><<<dim3(1024), dim3(256), 0, stream>>>(
        Bubf, W2bf, y_out, N2, Dv, sigbf);
}

// Round 7
// 224.533 us; speedup vs baseline: 1.1136x; 1.0248x over previous
//
#include <hip/hip_runtime.h>
#include <math.h>

#define L_SEQ   2048
#define BATCH_N 8
#define H_DIM   1024
#define P_DIM   512
#define M_DIM   (BATCH_N * L_SEQ)   // 16384
#define N2      1024                // packed complex width (re | im)
#define NC      32                  // scan chunks
#define T_CHUNK 64                  // L_SEQ / NC

typedef __attribute__((ext_vector_type(8))) __bf16 bf16x8;
typedef __attribute__((ext_vector_type(4))) float f32x4;

__device__ __forceinline__ unsigned f2bf_bits(float f) {
    unsigned u = __builtin_bit_cast(unsigned, f);
    return (u + 0x7fffu + ((u >> 16) & 1u)) >> 16;   // RNE
}
__device__ __forceinline__ float bf_lo(unsigned v) {
    return __builtin_bit_cast(float, v << 16);
}
__device__ __forceinline__ float bf_hi(unsigned v) {
    return __builtin_bit_cast(float, v & 0xffff0000u);
}
__device__ __forceinline__ float bf2f(unsigned short u) {
    return __builtin_bit_cast(float, (unsigned)u << 16);
}

#define ASYNC_COPY16(gsrc, ldst)                                            \
    __builtin_amdgcn_global_load_lds(                                       \
        (__attribute__((address_space(1))) void*)(gsrc),                    \
        (__attribute__((address_space(3))) void*)(ldst), 16, 0, 0)

// ---------------------------------------------------------------------------
// prep: fused setup_lam + build_W + convert_sig (3 launches -> 1).
// Round-5 calibration: one tiny kernel + launch ~= 6 us of pipeline time.
// NOTE round 6: the COOPERATIVE scan fusion hung the container -- reverted;
// this plain-launch prep fusion is the safe half and is kept.
//   blocks [0, 16384)        : convert signal f32 -> bf16 (4 elem/thread)
//   blocks [16384, 20480)    : build W1/W2; W1-half recomputes lam inline
//   blocks [20480, 20482)    : write lam_re/lam_im buffer for the scan
// lam buffer: [lam_re(512) | lam_im(512)]  (fp32)
// ---------------------------------------------------------------------------
#define NB_CONV 16384
#define NB_W    4096

__global__ __launch_bounds__(256) void prep(
    const float* __restrict__ signal, unsigned short* __restrict__ sigbf,
    const float* __restrict__ Lre_in, const float* __restrict__ Lim_in,
    const float* __restrict__ log_step,
    const float* __restrict__ B, const float* __restrict__ C,
    unsigned short* __restrict__ W1, unsigned short* __restrict__ W2,
    float* __restrict__ lam)
{
    int bid = blockIdx.x;
    if (bid < NB_CONV) {
        size_t i = ((size_t)bid * 256 + threadIdx.x) * 4;
        float4 v = *(const float4*)(signal + i);
        ushort4 o;
        o.x = (unsigned short)f2bf_bits(v.x);
        o.y = (unsigned short)f2bf_bits(v.y);
        o.z = (unsigned short)f2bf_bits(v.z);
        o.w = (unsigned short)f2bf_bits(v.w);
        *(ushort4*)(sigbf + i) = o;
    } else if (bid < NB_CONV + NB_W) {
        int idx = (bid - NB_CONV) * 256 + threadIdx.x;
        if (idx < P_DIM * H_DIM) {                   // W1 half: idx over P*H
            int p = idx >> 10;
            int h = idx & (H_DIM - 1);
            float step = expf(log_step[p]);
            float c = Lre_in[p];
            float d = Lim_in[p];
            float mag = expf(c * step);
            float ang = d * step;
            float lr = mag * cosf(ang);
            float li = mag * sinf(ang);
            float a = lr - 1.0f, bb = li;
            float inv = 1.0f / (c * c + d * d);
            float gre = (a * c + bb * d) * inv;
            float gim = (bb * c - a * d) * inv;
            float bre = B[(size_t)idx * 2];
            float bim = B[(size_t)idx * 2 + 1];
            W1[(size_t)p * H_DIM + h]           = (unsigned short)f2bf_bits(gre * bre - gim * bim);
            W1[(size_t)(P_DIM + p) * H_DIM + h] = (unsigned short)f2bf_bits(gre * bim + gim * bre);
        } else {                                     // W2 half: idx over H*P
            int j = idx - P_DIM * H_DIM;
            int h = j >> 9;
            int p = j & (P_DIM - 1);
            float cre = C[(size_t)j * 2];
            float cim = C[(size_t)j * 2 + 1];
            W2[(size_t)h * N2 + p]         = (unsigned short)f2bf_bits( 2.0f * cre);
            W2[(size_t)h * N2 + P_DIM + p] = (unsigned short)f2bf_bits(-2.0f * cim);
        }
    } else {
        int p = (bid - (NB_CONV + NB_W)) * 256 + threadIdx.x;
        if (p < P_DIM) {
            float step = expf(log_step[p]);
            float c = Lre_in[p];
            float d = Lim_in[p];
            float mag = expf(c * step);
            float ang = d * step;
            lam[p]         = mag * cosf(ang);
            lam[P_DIM + p] = mag * sinf(ang);
        }
    }
}

// ---------------------------------------------------------------------------
// bf16 MFMA GEMM (round-0 verified structure -- best measured: 44 us).
// Out[m][n] = sum_k A[m][k]*W[n][k].
// A: M x K bf16 row-major, W: N x K bf16 row-major (K = 1024).
// Block tile 128(m) x 128(n), BK=64, LDS 32 KB. 256 thr = 4 waves in 2x2;
// wave tile 64x64 = 4x4 frags of 16x16x32 MFMA (verified layout).
// Grid 1024, __launch_bounds__(256,4) -> 4 blocks/CU (16 waves): barrier
// drains overlap across blocks.
// LDS k-slot swizzle: slot' = (slot + (row>>1)) & 7, via rotating the
// *global* source quad per lane at stage time. NOTE (rounds 1-3 A/B):
// SQ_LDS_BANK_CONFLICT is a constant 4 cyc per ds_read_b128 under ANY
// swizzle -- structural wave64-b128 cost, not mis-banking. Do not chase.
// XCD swizzle: XCD x owns m-blocks [16x, 16x+16); 8 n-blocks consecutive.
// MODE 0: bf16 out via LDS-transposed coalesced 16B stores (2 phases).
// MODE 1: f32 out, + D[col]*bf2f(SigBf[row][col]) fused.
// ---------------------------------------------------------------------------
template <int MODE>
__global__ __launch_bounds__(256, 4) void gemm_mfma(
    const unsigned short* __restrict__ A,
    const unsigned short* __restrict__ W,
    void* __restrict__ Out, int K,
    const float* __restrict__ Dvec, const unsigned short* __restrict__ SigBf)
{
    __shared__ unsigned short smem[128 * 64 * 2];   // As 16K | Ws 16K
    unsigned short* As = smem;
    unsigned short* Ws = smem + 128 * 64;

    const int tid  = threadIdx.x;
    const int lane = tid & 63;
    const int wid  = tid >> 6;
    const int wm   = wid >> 1;     // 0..1
    const int wn   = wid & 1;      // 0..1

    // XCD swizzle: 128 m-blocks x 8 n-blocks, XCD x -> m-blocks [16x,16x+16)
    const int id  = blockIdx.x;
    const int xcd = id & 7;
    const int j   = id >> 3;              // 0..127
    const int mb  = xcd * 16 + (j >> 3);  // m-block (128 rows)
    const int nb  = j & 7;                // n-block (128 cols)
    const int m0 = mb * 128;
    const int n0 = nb * 128;

    // --- staging geometry (swizzled) --------------------------------------
    const int srow = tid >> 3;                                  // 0..31
    const int qg   = ((tid & 7) - ((tid >> 4) & 7)) & 7;        // const/lane
    const unsigned short* Abase = A + (size_t)(m0 + srow) * K + qg * 8;
    const unsigned short* Wbase = W + (size_t)(n0 + srow) * K + qg * 8;

    const int fr = lane & 15;        // m-row / n-col within 16
    const int fq = (lane >> 4) & 3;  // k-quad within 32
    const int sw = fr >> 1;          // swizzle rotation for this lane

    f32x4 acc[4][4] = {};

    for (int k0 = 0; k0 < K; k0 += 64) {
        __syncthreads();
        #pragma unroll
        for (int i = 0; i < 4; ++i)      // A: 1024 chunks (128 rows x 8 slots)
            ASYNC_COPY16(Abase + (size_t)(i * 32) * K + k0,
                         As + (size_t)(i * 256 + wid * 64) * 8);
        #pragma unroll
        for (int i = 0; i < 4; ++i)      // W: 1024 chunks
            ASYNC_COPY16(Wbase + (size_t)(i * 32) * K + k0,
                         Ws + (size_t)(i * 256 + wid * 64) * 8);
        __syncthreads();

        #pragma unroll
        for (int kk = 0; kk < 2; ++kk) {
            bf16x8 af[4], wf[4];
            #pragma unroll
            for (int mi = 0; mi < 4; ++mi) {
                int row = wm * 64 + mi * 16 + fr;
                int sl  = (kk * 4 + fq + sw) & 7;
                af[mi] = *(const bf16x8*)&As[(size_t)row * 64 + sl * 8];
            }
            #pragma unroll
            for (int ni = 0; ni < 4; ++ni) {
                int row = wn * 64 + ni * 16 + fr;
                int sl  = (kk * 4 + fq + sw) & 7;
                wf[ni] = *(const bf16x8*)&Ws[(size_t)row * 64 + sl * 8];
            }
            #pragma unroll
            for (int mi = 0; mi < 4; ++mi)
                #pragma unroll
                for (int ni = 0; ni < 4; ++ni)
                    acc[mi][ni] = __builtin_amdgcn_mfma_f32_16x16x32_bf16(
                        af[mi], wf[ni], acc[mi][ni], 0, 0, 0);
        }
    }

    // C/D layout (m89): col = lane&15, row = (lane>>4)*4 + reg
    if (MODE == 0) {
        // bf16 out: transpose through LDS (two 64x128 half-tiles, 16 KB)
        unsigned short* T = smem;
        #pragma unroll
        for (int h = 0; h < 2; ++h) {
            __syncthreads();       // prior LDS readers done
            if (wm == h) {
                #pragma unroll
                for (int mi = 0; mi < 4; ++mi)
                    #pragma unroll
                    for (int ni = 0; ni < 4; ++ni)
                        #pragma unroll
                        for (int r = 0; r < 4; ++r) {
                            int lrow = mi * 16 + fq * 4 + r;      // 0..63
                            int lcol = wn * 64 + ni * 16 + fr;    // 0..127
                            T[lrow * 128 + lcol] =
                                (unsigned short)f2bf_bits(acc[mi][ni][r]);
                        }
            }
            __syncthreads();
            // 64 rows x 128 cols = 1024 chunks of 8 ushorts (16 B)
            #pragma unroll
            for (int jj = 0; jj < 4; ++jj) {
                int chunk = jj * 256 + tid;        // 0..1023
                int row = chunk >> 4;              // 0..63
                int co  = (chunk & 15) * 8;        // 0..120
                *(ulonglong2*)((unsigned short*)Out +
                    (size_t)(m0 + h * 64 + row) * 1024 + n0 + co) =
                    *(const ulonglong2*)&T[row * 128 + co];
            }
        }
    } else {
        float Dl[4];
        #pragma unroll
        for (int ni = 0; ni < 4; ++ni)
            Dl[ni] = Dvec[n0 + wn * 64 + ni * 16 + fr];
        #pragma unroll
        for (int mi = 0; mi < 4; ++mi) {
            #pragma unroll
            for (int ni = 0; ni < 4; ++ni) {
                #pragma unroll
                for (int r = 0; r < 4; ++r) {
                    int row = m0 + wm * 64 + mi * 16 + fq * 4 + r;
                    int col = n0 + wn * 64 + ni * 16 + fr;
                    float v = acc[mi][ni][r];
                    v = fmaf(Dl[ni], bf2f(SigBf[(size_t)row * 1024 + col]), v);
                    ((float*)Out)[(size_t)row * 1024 + col] = v;
                }
            }
        }
    }
}

// ---------------------------------------------------------------------------
// Scan pass A: per (b, chunk) local scan (zero init) -> chunk-end sums.
// (round-0/5 verified version)
// ---------------------------------------------------------------------------
__global__ __launch_bounds__(256) void scan_sums(
    const unsigned short* __restrict__ Bu, const float* __restrict__ lam,
    float* __restrict__ S)
{
    int b = blockIdx.x, c = blockIdx.y, t = threadIdx.x;
    int p0 = 2 * t, p1 = 2 * t + 1;
    float lr0 = lam[p0], li0 = lam[P_DIM + p0];
    float lr1 = lam[p1], li1 = lam[P_DIM + p1];
    const unsigned* base =
        (const unsigned*)(Bu + ((size_t)b * L_SEQ + (size_t)c * T_CHUNK) * N2);
    float xr0 = 0, xi0 = 0, xr1 = 0, xi1 = 0;
    for (int j0 = 0; j0 < T_CHUNK; j0 += 8) {
        unsigned R[8], I[8];
        #pragma unroll
        for (int j = 0; j < 8; ++j) {
            R[j] = base[(size_t)(j0 + j) * 512 + t];
            I[j] = base[(size_t)(j0 + j) * 512 + 256 + t];
        }
        #pragma unroll
        for (int j = 0; j < 8; ++j) {
            float nr0 = fmaf(lr0, xr0, fmaf(-li0, xi0, bf_lo(R[j])));
            float ni0 = fmaf(lr0, xi0, fmaf( li0, xr0, bf_lo(I[j])));
            float nr1 = fmaf(lr1, xr1, fmaf(-li1, xi1, bf_hi(R[j])));
            float ni1 = fmaf(lr1, xi1, fmaf( li1, xr1, bf_hi(I[j])));
            xr0 = nr0; xi0 = ni0; xr1 = nr1; xi1 = ni1;
        }
    }
    float* Sb = S + ((size_t)(b * NC + c) * 2) * P_DIM;
    Sb[p0] = xr0; Sb[p1] = xr1;
    Sb[P_DIM + p0] = xi0; Sb[P_DIM + p1] = xi1;
}

// ---------------------------------------------------------------------------
// Pass B+C fused (round-5 verified): each (b,c) block derives its OWN
// carry-in from S via a 31-step Horner recurrence (statically preloaded
// float2 regs, predicated capture at k==c), then applies the chunk scan and
// overwrites Bu with xs (bf16); emits state.
// ---------------------------------------------------------------------------
__global__ __launch_bounds__(256) void scan_apply(
    unsigned short* __restrict__ Bu, const float* __restrict__ lam,
    const float* __restrict__ S, float* __restrict__ out_state,
    int interleaved)
{
    int b = blockIdx.x, c = blockIdx.y, t = threadIdx.x;
    int p0 = 2 * t, p1 = 2 * t + 1;
    float lr0 = lam[p0], li0 = lam[P_DIM + p0];
    float lr1 = lam[p1], li1 = lam[P_DIM + p1];

    // P = lam^T_CHUNK via 6 squarings (per p)
    float pr0 = lr0, pi0 = li0, pr1 = lr1, pi1 = li1;
    #pragma unroll
    for (int i = 0; i < 6; ++i) {
        float a0 = pr0 * pr0 - pi0 * pi0, b0 = 2.0f * pr0 * pi0;
        float a1 = pr1 * pr1 - pi1 * pi1, b1 = 2.0f * pr1 * pi1;
        pr0 = a0; pi0 = b0; pr1 = a1; pi1 = b1;
    }

    // preload S[k], k=0..30 (float2: consecutive p0,p1) -- static unroll
    float2 sre[NC - 1], sim[NC - 1];
    #pragma unroll
    for (int k = 0; k < NC - 1; ++k) {
        const float* Sb = S + ((size_t)(b * NC + k) * 2) * P_DIM;
        sre[k] = *(const float2*)&Sb[p0];
        sim[k] = *(const float2*)&Sb[P_DIM + p0];
    }

    // Horner prefix with predicated capture: cin[c]
    float xr0 = 0, xi0 = 0, xr1 = 0, xi1 = 0;
    float cr0 = 0, ci0 = 0, cr1 = 0, ci1 = 0;
    #pragma unroll
    for (int k = 0; k < NC - 1; ++k) {
        if (k == c) { cr0 = xr0; ci0 = xi0; cr1 = xr1; ci1 = xi1; }
        float nr0 = fmaf(pr0, xr0, fmaf(-pi0, xi0, sre[k].x));
        float ni0 = fmaf(pr0, xi0, fmaf( pi0, xr0, sim[k].x));
        float nr1 = fmaf(pr1, xr1, fmaf(-pi1, xi1, sre[k].y));
        float ni1 = fmaf(pr1, xi1, fmaf( pi1, xr1, sim[k].y));
        xr0 = nr0; xi0 = ni0; xr1 = nr1; xi1 = ni1;
    }
    if (c == NC - 1) { cr0 = xr0; ci0 = xi0; cr1 = xr1; ci1 = xi1; }

    // apply chunk scan starting from cin
    xr0 = cr0; xi0 = ci0; xr1 = cr1; xi1 = ci1;
    unsigned* base =
        (unsigned*)(Bu + ((size_t)b * L_SEQ + (size_t)c * T_CHUNK) * N2);
    for (int j0 = 0; j0 < T_CHUNK; j0 += 8) {
        unsigned R[8], I[8];
        #pragma unroll
        for (int j = 0; j < 8; ++j) {
            R[j] = base[(size_t)(j0 + j) * 512 + t];
            I[j] = base[(size_t)(j0 + j) * 512 + 256 + t];
        }
        #pragma unroll
        for (int j = 0; j < 8; ++j) {
            float nr0 = fmaf(lr0, xr0, fmaf(-li0, xi0, bf_lo(R[j])));
            float ni0 = fmaf(lr0, xi0, fmaf( li0, xr0, bf_lo(I[j])));
            float nr1 = fmaf(lr1, xr1, fmaf(-li1, xi1, bf_hi(R[j])));
            float ni1 = fmaf(lr1, xi1, fmaf( li1, xr1, bf_hi(I[j])));
            xr0 = nr0; xi0 = ni0; xr1 = nr1; xi1 = ni1;
            R[j] = f2bf_bits(nr0) | (f2bf_bits(nr1) << 16);
            I[j] = f2bf_bits(ni0) | (f2bf_bits(ni1) << 16);
        }
        #pragma unroll
        for (int j = 0; j < 8; ++j) {
            base[(size_t)(j0 + j) * 512 + t]       = R[j];
            base[(size_t)(j0 + j) * 512 + 256 + t] = I[j];
        }
    }
    if (c == NC - 1) {
        if (interleaved) {
            out_state[((size_t)b * P_DIM + p0) * 2]     = xr0;
            out_state[((size_t)b * P_DIM + p0) * 2 + 1] = xi0;
            out_state[((size_t)b * P_DIM + p1) * 2]     = xr1;
            out_state[((size_t)b * P_DIM + p1) * 2 + 1] = xi1;
        } else {
            out_state[(size_t)b * P_DIM + p0] = xr0;
            out_state[(size_t)b * P_DIM + p1] = xr1;
        }
    }
}

// ---------------------------------------------------------------------------
extern "C" void kernel_launch(void* const* d_in, const int* in_sizes, int n_in,
                              void* d_out, int out_size, void* d_ws, size_t ws_size,
                              hipStream_t stream)
{
    const float* signal   = (const float*)d_in[0];
    // d_in[1] = prev_state: never reaches the scan's b-component -> no effect
    const float* Lre      = (const float*)d_in[2];
    const float* Lim      = (const float*)d_in[3];
    const float* B        = (const float*)d_in[4];
    const float* C        = (const float*)d_in[5];
    const float* Dv       = (const float*)d_in[6];
    const float* log_step = (const float*)d_in[7];

    // ws layout (bytes)
    char* ws = (char*)d_ws;
    unsigned short* sigbf = (unsigned short*)ws;                      // 32 MB
    unsigned short* Bubf  = (unsigned short*)(ws + 33554432);         // 32 MB
    unsigned short* W1bf  = (unsigned short*)(ws + 67108864);         // 2 MB
    unsigned short* W2bf  = (unsigned short*)(ws + 69206016);         // 2 MB
    float*          lam   = (float*)(ws + 71303168);                  // 8 KB
    float*          S     = (float*)(ws + 71311360);                  // 512 KB
    size_t need = 71835648;
    if (ws_size < need) return;

    float* y_out = (float*)d_out;
    float* state_out = y_out + (size_t)M_DIM * H_DIM;
    int interleaved = (out_size - M_DIM * H_DIM) >= 2 * BATCH_N * P_DIM;

    // prep: convert + build_W + lam  (one kernel, 20482 blocks)
    prep<<<dim3(NB_CONV + NB_W + 2), dim3(256), 0, stream>>>(
        signal, sigbf, Lre, Lim, log_step, B, C, W1bf, W2bf, lam);

    // GEMM1: Bu[m][n] = sum_h sig[m][h] * W1[n][h]   (bf16 out)
    gemm_mfma<0><<<dim3(1024), dim3(256), 0, stream>>>(
        sigbf, W1bf, Bubf, H_DIM, nullptr, nullptr);

    scan_sums<<<dim3(BATCH_N, NC), dim3(256), 0, stream>>>(Bubf, lam, S);
    scan_apply<<<dim3(BATCH_N, NC), dim3(256), 0, stream>>>(
        Bubf, lam, S, state_out, interleaved);

    // GEMM2: y[m][h] = sum_k xs[m][k]*W2[h][k] + D[h]*sig[m][h]  (fp32 out)
    gemm_mfma<1><<<dim3(1024), dim3(256), 0, stream>>>(
        Bubf, W2bf, y_out, N2, Dv, sigbf);
}